// Round 1
// baseline (1504.928 us; speedup 1.0000x reference)
//
#include <hip/hip_runtime.h>
#include <math.h>

#define N_PTS 16384
#define HALF_N 8192
#define KK 16
#define NK (N_PTS * KK)
#define EPSV 1e-5f

#define KNN_SHARDS 8
#define KNN_QPB 32                    // queries per block (256 threads / 8 shards)
#define KNN_CPS (HALF_N / KNN_SHARDS) // candidates per shard = 1024

// ---- workspace layout (bytes) ----
#define OFF_IDX   0u                          // int32 [N_PTS][KK]        = 1 MB
#define OFF_PC    (1u << 20)                  // float4 [N_PTS] (x,y,z,d2) = 256 KB
#define OFF_X0    (OFF_PC + N_PTS * 16u)      // float [N_PTS][32]         = 2 MB
#define OFF_X1    (OFF_X0 + N_PTS * 32u * 4u) // float [N_PTS][32]         = 2 MB
#define OFF_PART  (OFF_X1 + N_PTS * 32u * 4u) // float [1024][64]          = 256 KB
#define OFF_STATS (OFF_PART + (NK / 256) * 64u * 4u) // float [64]

// ---------------- prep: pack (x,y,z,d2) ----------------
__global__ __launch_bounds__(256) void prep_kernel(const float* __restrict__ pts,
                                                   float4* __restrict__ pc) {
    int i = blockIdx.x * 256 + threadIdx.x;
    float x = pts[i * 5 + 1], y = pts[i * 5 + 2], z = pts[i * 5 + 3];
    // match reference d2 = sum(pos*pos) with plain (non-contracted) f32 ops
    float d2 = __fadd_rn(__fadd_rn(__fmul_rn(x, x), __fmul_rn(y, y)), __fmul_rn(z, z));
    pc[i] = make_float4(x, y, z, d2);
}

// ---------------- exact KNN (top-16 smallest dist, ties -> lower index) ----------------
__global__ __launch_bounds__(256) void knn_kernel(const float4* __restrict__ pc,
                                                  int* __restrict__ idx) {
    const int tid = threadIdx.x;
    const int q = tid & (KNN_QPB - 1);
    const int s = tid >> 5; // shard 0..7
    const int n = blockIdx.x * KNN_QPB + q;
    const int base = (n >= HALF_N) ? HALF_N : 0;
    const float4 p = pc[n];

    float bd[KK];
    int   bi[KK];
#pragma unroll
    for (int j = 0; j < KK; ++j) { bd[j] = 3.4e38f; bi[j] = 0x7FFFFFFF; }

    const int c0 = base + s * KNN_CPS;
    for (int t = 0; t < KNN_CPS; ++t) {
        const int ci = c0 + t;
        const float4 cp = pc[ci];
        // dist = (d2i + d2j) - 2*dot, exact reference ordering, no contraction
        float dot = __fadd_rn(__fadd_rn(__fmul_rn(p.x, cp.x), __fmul_rn(p.y, cp.y)),
                              __fmul_rn(p.z, cp.z));
        float dist = __fsub_rn(__fadd_rn(p.w, cp.w), __fmul_rn(2.0f, dot));
        // strict < : equal-dist later index loses => matches top_k lower-index-first
        if (dist < bd[KK - 1]) {
            bd[KK - 1] = dist; bi[KK - 1] = ci;
#pragma unroll
            for (int j = KK - 1; j >= 1; --j) {
                if (bd[j] < bd[j - 1]) {
                    float td = bd[j]; bd[j] = bd[j - 1]; bd[j - 1] = td;
                    int   ti = bi[j]; bi[j] = bi[j - 1]; bi[j - 1] = ti;
                }
            }
        }
    }

    __shared__ float sd[KNN_SHARDS][KNN_QPB][KK];
    __shared__ int   si[KNN_SHARDS][KNN_QPB][KK];
#pragma unroll
    for (int j = 0; j < KK; ++j) { sd[s][q][j] = bd[j]; si[s][q][j] = bi[j]; }
    __syncthreads();

    if (s == 0) {
        // merge shards 1..7 in increasing index order (preserves tie semantics)
        for (int sh = 1; sh < KNN_SHARDS; ++sh) {
#pragma unroll
            for (int e = 0; e < KK; ++e) {
                float d = sd[sh][q][e]; int ci = si[sh][q][e];
                if (d < bd[KK - 1]) {
                    bd[KK - 1] = d; bi[KK - 1] = ci;
#pragma unroll
                    for (int j = KK - 1; j >= 1; --j) {
                        if (bd[j] < bd[j - 1]) {
                            float td = bd[j]; bd[j] = bd[j - 1]; bd[j - 1] = td;
                            int   ti = bi[j]; bi[j] = bi[j - 1]; bi[j - 1] = ti;
                        }
                    }
                }
            }
        }
#pragma unroll
        for (int j = 0; j < KK; ++j) idx[n * KK + j] = bi[j];
    }
}

// ---------------- pass A: per-channel sum / sumsq of h over (N,K) ----------------
template <int IN_C, int OUT_C>
__global__ __launch_bounds__(256) void convA_kernel(const float* __restrict__ xin, int istride, int ioff,
                                                    const int* __restrict__ idx,
                                                    const float* __restrict__ W,
                                                    const float* __restrict__ b,
                                                    float* __restrict__ part) {
    __shared__ float s1[OUT_C];
    __shared__ float s2[OUT_C];
    const int tid = threadIdx.x;
    if (tid < OUT_C) { s1[tid] = 0.f; s2[tid] = 0.f; }
    __syncthreads();

    const int gt = blockIdx.x * 256 + tid;
    const int n = gt >> 4;
    float xn[IN_C], dx[IN_C];
    const float* rn = xin + n * istride + ioff;
#pragma unroll
    for (int e = 0; e < IN_C; ++e) xn[e] = rn[e];
    const int j = idx[gt];
    const float* rj = xin + j * istride + ioff;
#pragma unroll
    for (int e = 0; e < IN_C; ++e) dx[e] = rj[e] - xn[e];

    for (int c = 0; c < OUT_C; ++c) {
        float acc = b[c];
#pragma unroll
        for (int e = 0; e < IN_C; ++e) acc = fmaf(W[c * 2 * IN_C + e], xn[e], acc);
#pragma unroll
        for (int e = 0; e < IN_C; ++e) acc = fmaf(W[c * 2 * IN_C + IN_C + e], dx[e], acc);
        atomicAdd(&s1[c], acc);
        atomicAdd(&s2[c], acc * acc);
    }
    __syncthreads();
    if (tid < OUT_C) {
        part[blockIdx.x * 64 + tid]      = s1[tid];
        part[blockIdx.x * 64 + 32 + tid] = s2[tid];
    }
}

// ---------------- finalize: stats -> A[c]=rsig*g, B2[c]=t-mu*A ----------------
template <int OUT_C>
__global__ __launch_bounds__(256) void finalize_kernel(const float* __restrict__ part,
                                                       const float* __restrict__ g,
                                                       const float* __restrict__ t,
                                                       float* __restrict__ stats) {
    __shared__ float red[4][64];
    __shared__ float tot[64];
    const int tid = threadIdx.x;
    const int c2 = tid & 63, ch = tid >> 6;
    float s = 0.f;
    for (int bk = ch * 256; bk < ch * 256 + 256; ++bk) s += part[bk * 64 + c2];
    red[ch][c2] = s;
    __syncthreads();
    if (tid < 64) tot[tid] = red[0][tid] + red[1][tid] + red[2][tid] + red[3][tid];
    __syncthreads();
    if (tid < OUT_C) {
        const float inv = 1.0f / (float)NK;
        float mu  = tot[tid] * inv;
        float var = tot[32 + tid] * inv - mu * mu;
        float rs  = 1.0f / sqrtf(var + EPSV);
        float A   = rs * g[tid];
        stats[tid]      = A;
        stats[32 + tid] = t[tid] - mu * A;
    }
}

// ---------------- pass C: recompute h, normalize, relu, max over K ----------------
template <int IN_C, int OUT_C>
__global__ __launch_bounds__(256) void convC_kernel(const float* __restrict__ xin, int istride, int ioff,
                                                    const int* __restrict__ idx,
                                                    const float* __restrict__ W,
                                                    const float* __restrict__ b,
                                                    const float* __restrict__ stats,
                                                    float* __restrict__ xout) {
    const int tid = threadIdx.x;
    const int gt = blockIdx.x * 256 + tid;
    const int n = gt >> 4;
    float xn[IN_C], dx[IN_C];
    const float* rn = xin + n * istride + ioff;
#pragma unroll
    for (int e = 0; e < IN_C; ++e) xn[e] = rn[e];
    const int j = idx[gt];
    const float* rj = xin + j * istride + ioff;
#pragma unroll
    for (int e = 0; e < IN_C; ++e) dx[e] = rj[e] - xn[e];

    for (int c = 0; c < OUT_C; ++c) {
        float acc = b[c];
#pragma unroll
        for (int e = 0; e < IN_C; ++e) acc = fmaf(W[c * 2 * IN_C + e], xn[e], acc);
#pragma unroll
        for (int e = 0; e < IN_C; ++e) acc = fmaf(W[c * 2 * IN_C + IN_C + e], dx[e], acc);
        float v = fmaxf(fmaf(acc, stats[c], stats[32 + c]), 0.f);
        // max over the 16 k's (lanes sharing bits 4..5 of tid, k = tid&15)
        v = fmaxf(v, __shfl_xor(v, 1));
        v = fmaxf(v, __shfl_xor(v, 2));
        v = fmaxf(v, __shfl_xor(v, 4));
        v = fmaxf(v, __shfl_xor(v, 8));
        if ((tid & 15) == 0) xout[n * OUT_C + c] = v;
    }
}

extern "C" void kernel_launch(void* const* d_in, const int* in_sizes, int n_in,
                              void* d_out, int out_size, void* d_ws, size_t ws_size,
                              hipStream_t stream) {
    const float* pts = (const float*)d_in[0];
    const float* Wl[4], *bl[4], *gl[4], *tl[4];
    for (int l = 0; l < 4; ++l) {
        Wl[l] = (const float*)d_in[1 + 4 * l + 0];
        bl[l] = (const float*)d_in[1 + 4 * l + 1];
        gl[l] = (const float*)d_in[1 + 4 * l + 2];
        tl[l] = (const float*)d_in[1 + 4 * l + 3];
    }
    char* ws = (char*)d_ws;
    int*    idx   = (int*)(ws + OFF_IDX);
    float4* pc    = (float4*)(ws + OFF_PC);
    float*  x0    = (float*)(ws + OFF_X0);
    float*  x1    = (float*)(ws + OFF_X1);
    float*  part  = (float*)(ws + OFF_PART);
    float*  stats = (float*)(ws + OFF_STATS);
    float*  out   = (float*)d_out;

    prep_kernel<<<N_PTS / 256, 256, 0, stream>>>(pts, pc);
    knn_kernel<<<N_PTS / KNN_QPB, 256, 0, stream>>>(pc, idx);

    const int GA = NK / 256; // 1024 blocks for pass A / C

    // layer 0: 4 -> 16   (input = points[:,1:5], row stride 5, offset 1)
    convA_kernel<4, 16><<<GA, 256, 0, stream>>>(pts, 5, 1, idx, Wl[0], bl[0], part);
    finalize_kernel<16><<<1, 256, 0, stream>>>(part, gl[0], tl[0], stats);
    convC_kernel<4, 16><<<GA, 256, 0, stream>>>(pts, 5, 1, idx, Wl[0], bl[0], stats, x0);

    // layer 1: 16 -> 16
    convA_kernel<16, 16><<<GA, 256, 0, stream>>>(x0, 16, 0, idx, Wl[1], bl[1], part);
    finalize_kernel<16><<<1, 256, 0, stream>>>(part, gl[1], tl[1], stats);
    convC_kernel<16, 16><<<GA, 256, 0, stream>>>(x0, 16, 0, idx, Wl[1], bl[1], stats, x1);

    // layer 2: 16 -> 32
    convA_kernel<16, 32><<<GA, 256, 0, stream>>>(x1, 16, 0, idx, Wl[2], bl[2], part);
    finalize_kernel<32><<<1, 256, 0, stream>>>(part, gl[2], tl[2], stats);
    convC_kernel<16, 32><<<GA, 256, 0, stream>>>(x1, 16, 0, idx, Wl[2], bl[2], stats, x0);

    // layer 3: 32 -> 32  (writes d_out)
    convA_kernel<32, 32><<<GA, 256, 0, stream>>>(x0, 32, 0, idx, Wl[3], bl[3], part);
    finalize_kernel<32><<<1, 256, 0, stream>>>(part, gl[3], tl[3], stats);
    convC_kernel<32, 32><<<GA, 256, 0, stream>>>(x0, 32, 0, idx, Wl[3], bl[3], stats, out);
}

// Round 2
// 294.918 us; speedup vs baseline: 5.1029x; 5.1029x over previous
//
#include <hip/hip_runtime.h>
#include <math.h>

#define N_PTS 16384
#define HALF_N 8192
#define KK 16
#define NK (N_PTS * KK)
#define EPSV 1e-5f

// ---- KNN config: 16 queries x 16 shards per 256-thread block ----
#define QPB 16
#define SHARDS 16
#define MCAND (HALF_N / SHARDS) // 512 candidates per shard
#define BCAP 8                  // per-lane LDS candidate buffer

// ---- workspace layout (bytes) ----
#define OFF_IDX   0u                          // int32 [N_PTS][KK]        = 1 MB
#define OFF_PC    (1u << 20)                  // float4 [N_PTS] (x,y,z,d2) = 256 KB
#define OFF_X0    (OFF_PC + N_PTS * 16u)      // float [N_PTS][32]         = 2 MB
#define OFF_X1    (OFF_X0 + N_PTS * 32u * 4u) // float [N_PTS][32]         = 2 MB
#define OFF_PART  (OFF_X1 + N_PTS * 32u * 4u) // float [1024][64]          = 256 KB
#define OFF_STATS (OFF_PART + (NK / 256) * 64u * 4u) // float [64]

// ---------------- prep: pack (x,y,z,d2) ----------------
__global__ __launch_bounds__(256) void prep_kernel(const float* __restrict__ pts,
                                                   float4* __restrict__ pc) {
    int i = blockIdx.x * 256 + threadIdx.x;
    float x = pts[i * 5 + 1], y = pts[i * 5 + 2], z = pts[i * 5 + 3];
    float d2 = __fadd_rn(__fadd_rn(__fmul_rn(x, x), __fmul_rn(y, y)), __fmul_rn(z, z));
    pc[i] = make_float4(x, y, z, d2);
}

// ---------------- branch-free sorting primitives on u64 keys ----------------
__device__ __forceinline__ void ce64(unsigned long long& a, unsigned long long& b) {
    bool c = b < a;
    unsigned long long t = c ? b : a;
    b = c ? a : b;
    a = t;
}

// sort 8 ascending (Batcher odd-even mergesort, 19 CE)
__device__ __forceinline__ void sort8(unsigned long long b[8]) {
    ce64(b[0], b[1]); ce64(b[2], b[3]); ce64(b[4], b[5]); ce64(b[6], b[7]);
    ce64(b[0], b[2]); ce64(b[1], b[3]); ce64(b[4], b[6]); ce64(b[5], b[7]);
    ce64(b[1], b[2]); ce64(b[5], b[6]);
    ce64(b[0], b[4]); ce64(b[1], b[5]); ce64(b[2], b[6]); ce64(b[3], b[7]);
    ce64(b[2], b[4]); ce64(b[3], b[5]);
    ce64(b[1], b[2]); ce64(b[3], b[4]); ce64(b[5], b[6]);
}

// merge two ascending 16-lists, keep smallest 16 ascending in L (B clobbered)
__device__ __forceinline__ void merge16(unsigned long long L[16], unsigned long long B[16]) {
#pragma unroll
    for (int j = 0; j < 8; ++j) {
        unsigned long long a0 = L[j],      b0 = B[15 - j];
        unsigned long long a1 = L[15 - j], b1 = B[j];
        B[j]      = a0 < b0 ? a0 : b0;
        B[15 - j] = a1 < b1 ? a1 : b1;
    }
#pragma unroll
    for (int s = 8; s >= 1; s >>= 1) {
#pragma unroll
        for (int j = 0; j < 16; ++j)
            if (!(j & s)) ce64(B[j], B[j + s]);
    }
#pragma unroll
    for (int j = 0; j < 16; ++j) L[j] = B[j];
}

__device__ __forceinline__ void flushbuf(unsigned long long L[16],
                                         unsigned long long* buf,
                                         int& cnt, unsigned long long& tau) {
    unsigned long long b[8];
#pragma unroll
    for (int e = 0; e < 8; ++e) {
        unsigned long long v = buf[e];
        b[e] = (e < cnt) ? v : ~0ULL;
    }
    cnt = 0;
    sort8(b);
    unsigned long long B[16];
#pragma unroll
    for (int j = 0; j < 16; ++j) B[j] = (j < 8) ? b[j] : ~0ULL;
    merge16(L, B);
    tau = L[15];
}

// ---------------- exact KNN (top-16 smallest dist, ties -> lower index) ----------------
__global__ __launch_bounds__(256) void knn_kernel(const float4* __restrict__ pc,
                                                  int* __restrict__ idx) {
    // union: per-thread candidate buffers (scan phase, 256*9 u64) then
    // per-(shard,query) sorted lists (merge phase, 16*16*17 u64)
    __shared__ unsigned long long smem[SHARDS * QPB * 17];

    const int tid = threadIdx.x;
    const int q = tid & (QPB - 1);
    const int s = tid >> 4; // shard 0..15
    const int n = blockIdx.x * QPB + q;
    const int base = (n >= HALF_N) ? HALF_N : 0;
    const float4 p = pc[n];

    unsigned long long L[16];
#pragma unroll
    for (int j = 0; j < 16; ++j) L[j] = ~0ULL;

    unsigned long long* buf = &smem[tid * 9];
    int cnt = 0;
    unsigned long long tau = ~0ULL;

    const int c0 = base + s * MCAND;
#pragma unroll 4
    for (int t = 0; t < MCAND; ++t) {
        const int ci = c0 + t;
        const float4 cp = pc[ci]; // uniform per 16-lane group -> L1 broadcast
        float dot = __fadd_rn(__fadd_rn(__fmul_rn(p.x, cp.x), __fmul_rn(p.y, cp.y)),
                              __fmul_rn(p.z, cp.z));
        float dist = __fsub_rn(__fadd_rn(p.w, cp.w), __fmul_rn(2.0f, dot));
        unsigned u = __float_as_uint(dist);
        unsigned k32 = u ^ (unsigned)(((int)u >> 31) | 0x80000000);
        unsigned long long key = ((unsigned long long)k32 << 32) | (unsigned)ci;
        if (key < tau) { buf[cnt] = key; ++cnt; }
        if (__any(cnt >= BCAP)) flushbuf(L, buf, cnt, tau);
    }
    flushbuf(L, buf, cnt, tau);

    __syncthreads(); // scan buffers dead; reuse smem as sorted-list tree
#pragma unroll
    for (int j = 0; j < 16; ++j) smem[(s * QPB + q) * 17 + j] = L[j];
    __syncthreads();

    for (int step = SHARDS / 2; step >= 1; step >>= 1) {
        if (s < step) {
            unsigned long long B[16];
#pragma unroll
            for (int j = 0; j < 16; ++j) B[j] = smem[((s + step) * QPB + q) * 17 + j];
            merge16(L, B);
#pragma unroll
            for (int j = 0; j < 16; ++j) smem[(s * QPB + q) * 17 + j] = L[j];
        }
        __syncthreads();
    }

    if (s == 0) {
#pragma unroll
        for (int j = 0; j < 16; ++j) idx[n * KK + j] = (int)(L[j] & 0xffffffffu);
    }
}

// ---------------- pass A: per-channel sum / sumsq of h over (N,K) ----------------
template <int IN_C, int OUT_C>
__global__ __launch_bounds__(256) void convA_kernel(const float* __restrict__ xin, int istride, int ioff,
                                                    const int* __restrict__ idx,
                                                    const float* __restrict__ W,
                                                    const float* __restrict__ b,
                                                    float* __restrict__ part) {
    __shared__ float hbuf[OUT_C][257];
    constexpr int RED = 256 / OUT_C; // reducing threads per channel
    constexpr int SEG = OUT_C;       // elements each reducing thread sums
    __shared__ float pr1[OUT_C][RED + 1];
    __shared__ float pr2[OUT_C][RED + 1];

    const int tid = threadIdx.x;
    const int gt = blockIdx.x * 256 + tid;
    const int n = gt >> 4;
    float xn[IN_C], dx[IN_C];
    const float* rn = xin + n * istride + ioff;
#pragma unroll
    for (int e = 0; e < IN_C; ++e) xn[e] = rn[e];
    const int j = idx[gt];
    const float* rj = xin + j * istride + ioff;
#pragma unroll
    for (int e = 0; e < IN_C; ++e) dx[e] = rj[e] - xn[e];

    for (int c = 0; c < OUT_C; ++c) {
        float acc = b[c];
#pragma unroll
        for (int e = 0; e < IN_C; ++e) acc = fmaf(W[c * 2 * IN_C + e], xn[e], acc);
#pragma unroll
        for (int e = 0; e < IN_C; ++e) acc = fmaf(W[c * 2 * IN_C + IN_C + e], dx[e], acc);
        hbuf[c][tid] = acc;
    }
    __syncthreads();

    const int c = tid & (OUT_C - 1);
    const int ch = tid / OUT_C; // 0..RED-1
    float s1 = 0.f, s2 = 0.f;
#pragma unroll
    for (int i = 0; i < SEG; ++i) {
        float h = hbuf[c][ch * SEG + i];
        s1 += h;
        s2 += h * h;
    }
    pr1[c][ch] = s1;
    pr2[c][ch] = s2;
    __syncthreads();

    if (tid < OUT_C) {
        float t1 = 0.f, t2 = 0.f;
#pragma unroll
        for (int k = 0; k < RED; ++k) { t1 += pr1[tid][k]; t2 += pr2[tid][k]; }
        part[blockIdx.x * 64 + tid]      = t1;
        part[blockIdx.x * 64 + 32 + tid] = t2;
    }
}

// ---------------- finalize: stats -> A[c]=rsig*g, B2[c]=t-mu*A ----------------
template <int OUT_C>
__global__ __launch_bounds__(256) void finalize_kernel(const float* __restrict__ part,
                                                       const float* __restrict__ g,
                                                       const float* __restrict__ t,
                                                       float* __restrict__ stats) {
    __shared__ float red[4][64];
    __shared__ float tot[64];
    const int tid = threadIdx.x;
    const int c2 = tid & 63, ch = tid >> 6;
    float s = 0.f;
    for (int bk = ch * 256; bk < ch * 256 + 256; ++bk) s += part[bk * 64 + c2];
    red[ch][c2] = s;
    __syncthreads();
    if (tid < 64) tot[tid] = red[0][tid] + red[1][tid] + red[2][tid] + red[3][tid];
    __syncthreads();
    if (tid < OUT_C) {
        const float inv = 1.0f / (float)NK;
        float mu  = tot[tid] * inv;
        float var = tot[32 + tid] * inv - mu * mu;
        float rs  = 1.0f / sqrtf(var + EPSV);
        float A   = rs * g[tid];
        stats[tid]      = A;
        stats[32 + tid] = t[tid] - mu * A;
    }
}

// ---------------- pass C: recompute h, normalize, relu, max over K ----------------
template <int IN_C, int OUT_C>
__global__ __launch_bounds__(256) void convC_kernel(const float* __restrict__ xin, int istride, int ioff,
                                                    const int* __restrict__ idx,
                                                    const float* __restrict__ W,
                                                    const float* __restrict__ b,
                                                    const float* __restrict__ stats,
                                                    float* __restrict__ xout) {
    __shared__ float hbuf[OUT_C][257];
    const int tid = threadIdx.x;
    const int gt = blockIdx.x * 256 + tid;
    const int n = gt >> 4;
    float xn[IN_C], dx[IN_C];
    const float* rn = xin + n * istride + ioff;
#pragma unroll
    for (int e = 0; e < IN_C; ++e) xn[e] = rn[e];
    const int j = idx[gt];
    const float* rj = xin + j * istride + ioff;
#pragma unroll
    for (int e = 0; e < IN_C; ++e) dx[e] = rj[e] - xn[e];

    for (int c = 0; c < OUT_C; ++c) {
        float acc = b[c];
#pragma unroll
        for (int e = 0; e < IN_C; ++e) acc = fmaf(W[c * 2 * IN_C + e], xn[e], acc);
#pragma unroll
        for (int e = 0; e < IN_C; ++e) acc = fmaf(W[c * 2 * IN_C + IN_C + e], dx[e], acc);
        hbuf[c][tid] = acc;
    }
    __syncthreads();

    // max over K=16, then affine (A = rs*g > 0 so max commutes, fma monotone) + relu
    constexpr int ITER = (OUT_C * 16) / 256; // 1 for OUT_C=16, 2 for OUT_C=32
    const int n0 = blockIdx.x * 16;
#pragma unroll
    for (int r = 0; r < ITER; ++r) {
        const int c = tid & (OUT_C - 1);
        const int nl = (tid / OUT_C) + r * (256 / OUT_C);
        float m = hbuf[c][nl * 16];
#pragma unroll
        for (int k = 1; k < 16; ++k) m = fmaxf(m, hbuf[c][nl * 16 + k]);
        float v = fmaxf(fmaf(m, stats[c], stats[32 + c]), 0.f);
        xout[(n0 + nl) * OUT_C + c] = v;
    }
}

extern "C" void kernel_launch(void* const* d_in, const int* in_sizes, int n_in,
                              void* d_out, int out_size, void* d_ws, size_t ws_size,
                              hipStream_t stream) {
    const float* pts = (const float*)d_in[0];
    const float* Wl[4], *bl[4], *gl[4], *tl[4];
    for (int l = 0; l < 4; ++l) {
        Wl[l] = (const float*)d_in[1 + 4 * l + 0];
        bl[l] = (const float*)d_in[1 + 4 * l + 1];
        gl[l] = (const float*)d_in[1 + 4 * l + 2];
        tl[l] = (const float*)d_in[1 + 4 * l + 3];
    }
    char* ws = (char*)d_ws;
    int*    idx   = (int*)(ws + OFF_IDX);
    float4* pc    = (float4*)(ws + OFF_PC);
    float*  x0    = (float*)(ws + OFF_X0);
    float*  x1    = (float*)(ws + OFF_X1);
    float*  part  = (float*)(ws + OFF_PART);
    float*  stats = (float*)(ws + OFF_STATS);
    float*  out   = (float*)d_out;

    prep_kernel<<<N_PTS / 256, 256, 0, stream>>>(pts, pc);
    knn_kernel<<<N_PTS / QPB, 256, 0, stream>>>(pc, idx);

    const int GA = NK / 256; // 1024 blocks

    // layer 0: 4 -> 16   (input = points[:,1:5], row stride 5, offset 1)
    convA_kernel<4, 16><<<GA, 256, 0, stream>>>(pts, 5, 1, idx, Wl[0], bl[0], part);
    finalize_kernel<16><<<1, 256, 0, stream>>>(part, gl[0], tl[0], stats);
    convC_kernel<4, 16><<<GA, 256, 0, stream>>>(pts, 5, 1, idx, Wl[0], bl[0], stats, x0);

    // layer 1: 16 -> 16
    convA_kernel<16, 16><<<GA, 256, 0, stream>>>(x0, 16, 0, idx, Wl[1], bl[1], part);
    finalize_kernel<16><<<1, 256, 0, stream>>>(part, gl[1], tl[1], stats);
    convC_kernel<16, 16><<<GA, 256, 0, stream>>>(x0, 16, 0, idx, Wl[1], bl[1], stats, x1);

    // layer 2: 16 -> 32
    convA_kernel<16, 32><<<GA, 256, 0, stream>>>(x1, 16, 0, idx, Wl[2], bl[2], part);
    finalize_kernel<32><<<1, 256, 0, stream>>>(part, gl[2], tl[2], stats);
    convC_kernel<16, 32><<<GA, 256, 0, stream>>>(x1, 16, 0, idx, Wl[2], bl[2], stats, x0);

    // layer 3: 32 -> 32  (writes d_out)
    convA_kernel<32, 32><<<GA, 256, 0, stream>>>(x0, 32, 0, idx, Wl[3], bl[3], part);
    finalize_kernel<32><<<1, 256, 0, stream>>>(part, gl[3], tl[3], stats);
    convC_kernel<32, 32><<<GA, 256, 0, stream>>>(x0, 32, 0, idx, Wl[3], bl[3], stats, out);
}

// Round 4
// 271.165 us; speedup vs baseline: 5.5499x; 1.0876x over previous
//
#include <hip/hip_runtime.h>
#include <math.h>

typedef unsigned long long u64;

#define N_PTS 16384
#define HALF_N 8192
#define KK 16
#define NK (N_PTS * KK)
#define EPSV 1e-5f

// ---- KNN config: 16 queries x 16 shards per 256-thread block ----
#define QPB 16
#define SHARDS 16
#define MCAND (HALF_N / SHARDS) // 512 candidates per shard
#define CHUNK 4
#define FTHRESH 12              // flush when any lane has >=12 buffered (cap 16)

// ---- workspace layout (bytes) ----
#define OFF_IDX   0u                           // int32 [N_PTS][KK]         = 1 MB
#define OFF_PC    (1u << 20)                   // float4 [N_PTS]            = 256 KB
#define OFF_MA    (OFF_PC + N_PTS * 16u)       // m0 [N][16] / m3 lower half
#define OFF_MB    (OFF_MA + N_PTS * 16u * 4u)  // m1 [N][16] / m3 upper half
#define OFF_MC    (OFF_MB + N_PTS * 16u * 4u)  // m2 [N][32]                = 2 MB
#define OFF_PART  (OFF_MC + N_PTS * 32u * 4u)  // float [1024][64]          = 256 KB
#define OFF_STATS (OFF_PART + 1024u * 64u * 4u)// float [4][64]

// ---------------- prep: pack (x,y,z,d2) ----------------
__global__ __launch_bounds__(256) void prep_kernel(const float* __restrict__ pts,
                                                   float4* __restrict__ pc) {
    int i = blockIdx.x * 256 + threadIdx.x;
    float x = pts[i * 5 + 1], y = pts[i * 5 + 2], z = pts[i * 5 + 3];
    float d2 = __fadd_rn(__fadd_rn(__fmul_rn(x, x), __fmul_rn(y, y)), __fmul_rn(z, z));
    pc[i] = make_float4(x, y, z, d2);
}

// ---------------- branch-free sorting primitives on u64 keys ----------------
__device__ __forceinline__ void ce64(u64& a, u64& b) {
    bool c = b < a;
    u64 t = c ? b : a;
    b = c ? a : b;
    a = t;
}

// sort 8 ascending (Batcher odd-even mergesort, 19 CE)
__device__ __forceinline__ void sort8(u64* b) {
    ce64(b[0], b[1]); ce64(b[2], b[3]); ce64(b[4], b[5]); ce64(b[6], b[7]);
    ce64(b[0], b[2]); ce64(b[1], b[3]); ce64(b[4], b[6]); ce64(b[5], b[7]);
    ce64(b[1], b[2]); ce64(b[5], b[6]);
    ce64(b[0], b[4]); ce64(b[1], b[5]); ce64(b[2], b[6]); ce64(b[3], b[7]);
    ce64(b[2], b[4]); ce64(b[3], b[5]);
    ce64(b[1], b[2]); ce64(b[3], b[4]); ce64(b[5], b[6]);
}

// sort 16 ascending: two sort8 + bitonic merge
__device__ __forceinline__ void sort16(u64 b[16]) {
    sort8(b); sort8(b + 8);
#pragma unroll
    for (int j = 0; j < 8; ++j) ce64(b[j], b[15 - j]);
#pragma unroll
    for (int h = 0; h < 16; h += 8) {
        ce64(b[h + 0], b[h + 4]); ce64(b[h + 1], b[h + 5]);
        ce64(b[h + 2], b[h + 6]); ce64(b[h + 3], b[h + 7]);
        ce64(b[h + 0], b[h + 2]); ce64(b[h + 1], b[h + 3]);
        ce64(b[h + 4], b[h + 6]); ce64(b[h + 5], b[h + 7]);
        ce64(b[h + 0], b[h + 1]); ce64(b[h + 2], b[h + 3]);
        ce64(b[h + 4], b[h + 5]); ce64(b[h + 6], b[h + 7]);
    }
}

// merge two ascending 16-lists, keep smallest 16 ascending in L (B clobbered)
__device__ __forceinline__ void merge16(u64 L[16], u64 B[16]) {
#pragma unroll
    for (int j = 0; j < 8; ++j) {
        u64 a0 = L[j],      b0 = B[15 - j];
        u64 a1 = L[15 - j], b1 = B[j];
        B[j]      = a0 < b0 ? a0 : b0;
        B[15 - j] = a1 < b1 ? a1 : b1;
    }
#pragma unroll
    for (int s = 8; s >= 1; s >>= 1) {
#pragma unroll
        for (int j = 0; j < 16; ++j)
            if (!(j & s)) ce64(B[j], B[j + s]);
    }
#pragma unroll
    for (int j = 0; j < 16; ++j) L[j] = B[j];
}

// flush buffered raw (floatbits<<32|idx) entries: transform to monotone keys,
// sort, merge into L, refresh float threshold tauf (NaN while L unfilled)
__device__ __forceinline__ void flush16(u64 L[16], const u64* buf, int& cnt, float& tauf) {
    u64 b[16];
#pragma unroll
    for (int e = 0; e < 16; ++e) {
        u64 raw = buf[e];
        unsigned hi = (unsigned)(raw >> 32);
        unsigned mk = hi ^ ((unsigned)(((int)hi) >> 31) | 0x80000000u);
        u64 key = ((u64)mk << 32) | (raw & 0xffffffffULL);
        b[e] = (e < cnt) ? key : ~0ULL;
    }
    cnt = 0;
    sort16(b);
    merge16(L, b);
    unsigned k32 = (unsigned)(L[15] >> 32);
    unsigned xv = 0x80000000u | ((~((unsigned)(((int)k32) >> 31))) >> 1);
    tauf = __uint_as_float(k32 ^ xv); // inverse monotone map; sentinel -> NaN (accept all)
}

// ---------------- exact KNN (top-16 smallest dist, ties -> lower index) ----------------
__global__ __launch_bounds__(256) void knn_kernel(const float4* __restrict__ pc,
                                                  int* __restrict__ idx) {
    __shared__ u64 smem[256 * 17]; // lane buffers (cap 16, stride 17) then merge tree

    const int tid = threadIdx.x;
    const int q = tid & (QPB - 1);
    const int s = tid >> 4;
    const int n = blockIdx.x * QPB + q;
    const int base = (n >= HALF_N) ? HALF_N : 0;
    const float4 p = pc[n];

    u64 L[16];
#pragma unroll
    for (int j = 0; j < 16; ++j) L[j] = ~0ULL;

    u64* buf = &smem[tid * 17];
    int cnt = 0;
    float tauf = __uint_as_float(0x7fffffffu); // NaN: !(d > NaN) accepts all

    const int c0 = base + s * MCAND;
#pragma unroll 1
    for (int t0 = 0; t0 < MCAND; t0 += CHUNK) {
#pragma unroll
        for (int dt = 0; dt < CHUNK; ++dt) {
            const int ci = c0 + t0 + dt;
            const float4 cp = pc[ci];
            float dot = __fadd_rn(__fadd_rn(__fmul_rn(p.x, cp.x), __fmul_rn(p.y, cp.y)),
                                  __fmul_rn(p.z, cp.z));
            float dist = __fsub_rn(__fadd_rn(p.w, cp.w), __fmul_rn(2.0f, dot));
            if (!(dist > tauf)) { // ties admitted; exact select at flush
                buf[cnt] = ((u64)__float_as_uint(dist) << 32) | (unsigned)ci;
                ++cnt;
            }
        }
        if (__any(cnt >= FTHRESH)) flush16(L, buf, cnt, tauf);
        // invariant: cnt <= 11 after check, +4 per chunk -> <= 15 <= 16 cap
    }
    flush16(L, buf, cnt, tauf);

    // cross-shard bitonic merge tree in LDS
#pragma unroll
    for (int j = 0; j < 16; ++j) smem[tid * 17 + j] = L[j];
    __syncthreads();
    for (int step = SHARDS / 2; step >= 1; step >>= 1) {
        if (s < step) {
            u64 B[16];
#pragma unroll
            for (int j = 0; j < 16; ++j) B[j] = smem[((s + step) * QPB + q) * 17 + j];
            merge16(L, B);
#pragma unroll
            for (int j = 0; j < 16; ++j) smem[(s * QPB + q) * 17 + j] = L[j];
        }
        __syncthreads();
    }

    if (s == 0) {
#pragma unroll
        for (int j = 0; j < 16; ++j) idx[n * KK + j] = (int)(L[j] & 0xffffffffULL);
    }
}

// ============ per-layer conv: h once -> {part sums, raw per-point max} ============
// MODE 0: xin = pts (stride 5, offset 1, raw). MODE 1: xin = m_prev, apply
// relu(fma(., A, B2)) of the PREVIOUS layer on the fly (A>0 since g=1, so
// max-then-affine == affine-then-max; relu monotone).
template <int IN_C, int OUT_C, int MODE>
__global__ __launch_bounds__(256) void convS_kernel(const float* __restrict__ xin,
                                                    const float* __restrict__ statsPrev,
                                                    const int* __restrict__ idxg,
                                                    const float* __restrict__ W,
                                                    const float* __restrict__ bb,
                                                    float* __restrict__ part,
                                                    float* __restrict__ mout) {
    constexpr int RED = 256 / OUT_C;
    __shared__ float hbuf[OUT_C][257];
    __shared__ float pr1[OUT_C][RED + 1];
    __shared__ float pr2[OUT_C][RED + 1];
    __shared__ float2 sAB[IN_C];

    const int tid = threadIdx.x;
    const int gt = blockIdx.x * 256 + tid;
    const int n = gt >> 4;

    if (MODE == 1) {
        if (tid < IN_C) sAB[tid] = make_float2(statsPrev[tid], statsPrev[32 + tid]);
        __syncthreads();
    }

    float xn[IN_C], dx[IN_C];
    const int j = idxg[gt];
    if (MODE == 0) {
        const float* rn = xin + n * 5 + 1;
        const float* rj = xin + j * 5 + 1;
#pragma unroll
        for (int e = 0; e < IN_C; ++e) xn[e] = rn[e];
#pragma unroll
        for (int e = 0; e < IN_C; ++e) dx[e] = rj[e] - xn[e];
    } else {
        const float4* rn = (const float4*)(xin + n * IN_C);
        const float4* rj = (const float4*)(xin + j * IN_C);
#pragma unroll
        for (int e4 = 0; e4 < IN_C / 4; ++e4) {
            float4 a = rn[e4];
            float4 bq = rj[e4];
            float av[4] = {a.x, a.y, a.z, a.w};
            float bv[4] = {bq.x, bq.y, bq.z, bq.w};
#pragma unroll
            for (int u = 0; u < 4; ++u) {
                float2 ab = sAB[4 * e4 + u];
                float xv = fmaxf(fmaf(av[u], ab.x, ab.y), 0.f);
                float jv = fmaxf(fmaf(bv[u], ab.x, ab.y), 0.f);
                xn[4 * e4 + u] = xv;
                dx[4 * e4 + u] = jv - xv;
            }
        }
    }

    float h[OUT_C];
#pragma unroll
    for (int c = 0; c < OUT_C; ++c) {
        float acc = bb[c];
#pragma unroll
        for (int e = 0; e < IN_C; ++e) acc = fmaf(W[c * 2 * IN_C + e], xn[e], acc);
#pragma unroll
        for (int e = 0; e < IN_C; ++e) acc = fmaf(W[c * 2 * IN_C + IN_C + e], dx[e], acc);
        h[c] = acc;
    }

    // ---- raw max over K=16 via shfl (16 consecutive lanes share n) ----
    {
        const int kq = tid & 15;
        if (OUT_C == 32) {
            float w0 = 0.f, w1 = 0.f;
#pragma unroll
            for (int c = 0; c < OUT_C; ++c) {
                float v = h[c];
                v = fmaxf(v, __shfl_xor(v, 1));
                v = fmaxf(v, __shfl_xor(v, 2));
                v = fmaxf(v, __shfl_xor(v, 4));
                v = fmaxf(v, __shfl_xor(v, 8));
                if (c == 2 * kq)     w0 = v;
                if (c == 2 * kq + 1) w1 = v;
            }
            *reinterpret_cast<float2*>(mout + n * 32 + 2 * kq) = make_float2(w0, w1);
        } else {
            float w0 = 0.f;
#pragma unroll
            for (int c = 0; c < OUT_C; ++c) {
                float v = h[c];
                v = fmaxf(v, __shfl_xor(v, 1));
                v = fmaxf(v, __shfl_xor(v, 2));
                v = fmaxf(v, __shfl_xor(v, 4));
                v = fmaxf(v, __shfl_xor(v, 8));
                if (c == kq) w0 = v;
            }
            mout[n * 16 + kq] = w0;
        }
    }

    // ---- block reduce sum/sumsq (deterministic) ----
#pragma unroll
    for (int c = 0; c < OUT_C; ++c) hbuf[c][tid] = h[c];
    __syncthreads();
    {
        const int c2 = tid & (OUT_C - 1);
        const int ch = tid / OUT_C;
        float s1 = 0.f, s2 = 0.f;
#pragma unroll
        for (int i = 0; i < OUT_C; ++i) {
            float hh = hbuf[c2][ch * OUT_C + i];
            s1 += hh; s2 += hh * hh;
        }
        pr1[c2][ch] = s1;
        pr2[c2][ch] = s2;
    }
    __syncthreads();
    if (tid < OUT_C) {
        float t1 = 0.f, t2 = 0.f;
#pragma unroll
        for (int k = 0; k < RED; ++k) { t1 += pr1[tid][k]; t2 += pr2[tid][k]; }
        part[blockIdx.x * 64 + tid]      = t1;
        part[blockIdx.x * 64 + 32 + tid] = t2;
    }
}

// ---------------- finalize: part -> A[c]=rs*g, B2[c]=t-mu*A ----------------
template <int OUT_C>
__global__ __launch_bounds__(256) void finalize_kernel(const float* __restrict__ part,
                                                       const float* __restrict__ g,
                                                       const float* __restrict__ t,
                                                       float* __restrict__ statsL) {
    __shared__ float red[4][64];
    __shared__ float tot[64];
    const int tid = threadIdx.x;
    const int c2 = tid & 63, ch = tid >> 6;
    float s = 0.f;
    for (int bk = ch * 256; bk < ch * 256 + 256; ++bk) s += part[bk * 64 + c2];
    red[ch][c2] = s;
    __syncthreads();
    if (tid < 64) tot[tid] = red[0][tid] + red[1][tid] + red[2][tid] + red[3][tid];
    __syncthreads();
    if (tid < OUT_C) {
        const float inv = 1.0f / (float)NK;
        float mu  = tot[tid] * inv;
        float var = tot[32 + tid] * inv - mu * mu;
        float rs  = 1.0f / sqrtf(var + EPSV);
        float A   = rs * g[tid];
        statsL[tid]      = A;
        statsL[32 + tid] = t[tid] - mu * A;
    }
}

// ---------------- final apply: out = relu(fma(m3, A, B2)) ----------------
__global__ __launch_bounds__(256) void apply_kernel(const float* __restrict__ m,
                                                    const float* __restrict__ st,
                                                    float* __restrict__ out) {
    const int i = blockIdx.x * 256 + threadIdx.x;
    float4 mv = ((const float4*)m)[i];
    const int c0 = (i * 4) & 31;
    float4 Av = *(const float4*)(st + c0);
    float4 Bv = *(const float4*)(st + 32 + c0);
    float4 o;
    o.x = fmaxf(fmaf(mv.x, Av.x, Bv.x), 0.f);
    o.y = fmaxf(fmaf(mv.y, Av.y, Bv.y), 0.f);
    o.z = fmaxf(fmaf(mv.z, Av.z, Bv.z), 0.f);
    o.w = fmaxf(fmaf(mv.w, Av.w, Bv.w), 0.f);
    ((float4*)out)[i] = o;
}

extern "C" void kernel_launch(void* const* d_in, const int* in_sizes, int n_in,
                              void* d_out, int out_size, void* d_ws, size_t ws_size,
                              hipStream_t stream) {
    const float* pts = (const float*)d_in[0];
    const float* Wl[4], *bl[4], *gl[4], *tl[4];
    for (int l = 0; l < 4; ++l) {
        Wl[l] = (const float*)d_in[1 + 4 * l + 0];
        bl[l] = (const float*)d_in[1 + 4 * l + 1];
        gl[l] = (const float*)d_in[1 + 4 * l + 2];
        tl[l] = (const float*)d_in[1 + 4 * l + 3];
    }
    char* ws = (char*)d_ws;
    int*    idx   = (int*)(ws + OFF_IDX);
    float4* pc    = (float4*)(ws + OFF_PC);
    float*  m0    = (float*)(ws + OFF_MA); // [N][16]
    float*  m1    = (float*)(ws + OFF_MB); // [N][16]
    float*  m2    = (float*)(ws + OFF_MC); // [N][32]
    float*  m3    = (float*)(ws + OFF_MA); // [N][32] reuses MA|MB (m0,m1 dead)
    float*  part  = (float*)(ws + OFF_PART);
    float*  stats = (float*)(ws + OFF_STATS); // [4][64]
    float*  out   = (float*)d_out;

    prep_kernel<<<N_PTS / 256, 256, 0, stream>>>(pts, pc);
    knn_kernel<<<N_PTS / QPB, 256, 0, stream>>>(pc, idx);

    const int GA = NK / 256; // 1024 blocks

    // layer 0: 4 -> 16 (raw pts input)
    convS_kernel<4, 16, 0><<<GA, 256, 0, stream>>>(pts, nullptr, idx, Wl[0], bl[0], part, m0);
    finalize_kernel<16><<<1, 256, 0, stream>>>(part, gl[0], tl[0], stats + 0);

    // layer 1: 16 -> 16 (m0 + layer-0 affine on the fly)
    convS_kernel<16, 16, 1><<<GA, 256, 0, stream>>>(m0, stats + 0, idx, Wl[1], bl[1], part, m1);
    finalize_kernel<16><<<1, 256, 0, stream>>>(part, gl[1], tl[1], stats + 64);

    // layer 2: 16 -> 32
    convS_kernel<16, 32, 1><<<GA, 256, 0, stream>>>(m1, stats + 64, idx, Wl[2], bl[2], part, m2);
    finalize_kernel<32><<<1, 256, 0, stream>>>(part, gl[2], tl[2], stats + 128);

    // layer 3: 32 -> 32 (writes m3 over MA|MB; m0/m1 dead)
    convS_kernel<32, 32, 1><<<GA, 256, 0, stream>>>(m2, stats + 128, idx, Wl[3], bl[3], part, m3);
    finalize_kernel<32><<<1, 256, 0, stream>>>(part, gl[3], tl[3], stats + 192);

    // out = relu(affine(m3))
    apply_kernel<<<(N_PTS * 32 / 4) / 256, 256, 0, stream>>>(m3, stats + 192, out);
}

// Round 5
// 255.412 us; speedup vs baseline: 5.8921x; 1.0617x over previous
//
#include <hip/hip_runtime.h>
#include <math.h>

typedef unsigned long long u64;

#define N_PTS 16384
#define HALF_N 8192
#define KK 16
#define NK (N_PTS * KK)
#define EPSV 1e-5f

// ---- KNN config: 16 queries x 16 shards per 256-thread block ----
#define QPB 16
#define SHARDS 16
#define MCAND (HALF_N / SHARDS) // 512 candidates per shard
#define CHUNK 4
#define FTHRESH 12              // flush when any lane has >=12 buffered (cap 16)

// ---- workspace layout (bytes) ----
#define OFF_IDX   0u                           // int32 [N_PTS][KK]         = 1 MB
#define OFF_PC    (1u << 20)                   // float4 [N_PTS]            = 256 KB
#define OFF_MA    (OFF_PC + N_PTS * 16u)       // m0 [N][16] / m3 lower half
#define OFF_MB    (OFF_MA + N_PTS * 16u * 4u)  // m1 [N][16] / m3 upper half
#define OFF_MC    (OFF_MB + N_PTS * 16u * 4u)  // m2 [N][32]                = 2 MB
#define OFF_PART  (OFF_MC + N_PTS * 32u * 4u)  // float [1024][64]          = 256 KB
#define OFF_STATS (OFF_PART + 1024u * 64u * 4u)// float [4][64]

// ---------------- prep: pack (x,y,z,d2) ----------------
__global__ __launch_bounds__(256) void prep_kernel(const float* __restrict__ pts,
                                                   float4* __restrict__ pc) {
    int i = blockIdx.x * 256 + threadIdx.x;
    float x = pts[i * 5 + 1], y = pts[i * 5 + 2], z = pts[i * 5 + 3];
    float d2 = __fadd_rn(__fadd_rn(__fmul_rn(x, x), __fmul_rn(y, y)), __fmul_rn(z, z));
    pc[i] = make_float4(x, y, z, d2);
}

// ---------------- branch-free sorting primitives on u64 keys ----------------
__device__ __forceinline__ void ce64(u64& a, u64& b) {
    bool c = b < a;
    u64 t = c ? b : a;
    b = c ? a : b;
    a = t;
}

// sort 8 ascending (Batcher odd-even mergesort, 19 CE)
__device__ __forceinline__ void sort8(u64* b) {
    ce64(b[0], b[1]); ce64(b[2], b[3]); ce64(b[4], b[5]); ce64(b[6], b[7]);
    ce64(b[0], b[2]); ce64(b[1], b[3]); ce64(b[4], b[6]); ce64(b[5], b[7]);
    ce64(b[1], b[2]); ce64(b[5], b[6]);
    ce64(b[0], b[4]); ce64(b[1], b[5]); ce64(b[2], b[6]); ce64(b[3], b[7]);
    ce64(b[2], b[4]); ce64(b[3], b[5]);
    ce64(b[1], b[2]); ce64(b[3], b[4]); ce64(b[5], b[6]);
}

// sort 16 ascending: two sort8 + bitonic merge
__device__ __forceinline__ void sort16(u64 b[16]) {
    sort8(b); sort8(b + 8);
#pragma unroll
    for (int j = 0; j < 8; ++j) ce64(b[j], b[15 - j]);
#pragma unroll
    for (int h = 0; h < 16; h += 8) {
        ce64(b[h + 0], b[h + 4]); ce64(b[h + 1], b[h + 5]);
        ce64(b[h + 2], b[h + 6]); ce64(b[h + 3], b[h + 7]);
        ce64(b[h + 0], b[h + 2]); ce64(b[h + 1], b[h + 3]);
        ce64(b[h + 4], b[h + 6]); ce64(b[h + 5], b[h + 7]);
        ce64(b[h + 0], b[h + 1]); ce64(b[h + 2], b[h + 3]);
        ce64(b[h + 4], b[h + 5]); ce64(b[h + 6], b[h + 7]);
    }
}

// merge two ascending 16-lists, keep smallest 16 ascending in L (B clobbered)
__device__ __forceinline__ void merge16(u64 L[16], u64 B[16]) {
#pragma unroll
    for (int j = 0; j < 8; ++j) {
        u64 a0 = L[j],      b0 = B[15 - j];
        u64 a1 = L[15 - j], b1 = B[j];
        B[j]      = a0 < b0 ? a0 : b0;
        B[15 - j] = a1 < b1 ? a1 : b1;
    }
#pragma unroll
    for (int s = 8; s >= 1; s >>= 1) {
#pragma unroll
        for (int j = 0; j < 16; ++j)
            if (!(j & s)) ce64(B[j], B[j + s]);
    }
#pragma unroll
    for (int j = 0; j < 16; ++j) L[j] = B[j];
}

// flush buffered raw (floatbits<<32|idx) entries: transform to monotone keys,
// sort, merge into L. Returns float-BITS of new 16th-best dist (uint-monotone
// for dists >= 0); sentinel L[15] maps to 0x7FFFFFFF (> +inf bits, atomicMin no-op).
__device__ __forceinline__ unsigned flush16(u64 L[16], const u64* buf, int& cnt) {
    u64 b[16];
#pragma unroll
    for (int e = 0; e < 16; ++e) {
        u64 raw = buf[e];
        unsigned hi = (unsigned)(raw >> 32);
        unsigned mk = hi ^ ((unsigned)(((int)hi) >> 31) | 0x80000000u);
        u64 key = ((u64)mk << 32) | (raw & 0xffffffffULL);
        b[e] = (e < cnt) ? key : ~0ULL;
    }
    cnt = 0;
    sort16(b);
    merge16(L, b);
    unsigned k32 = (unsigned)(L[15] >> 32);
    unsigned xv = 0x80000000u | ((~((unsigned)(((int)k32) >> 31))) >> 1);
    return k32 ^ xv; // inverse monotone map (float bits)
}

// ---------------- exact KNN (top-16 smallest dist, ties -> lower index) ----------------
// Shared per-query threshold: tauS[q] = min over the query's 16 shards of each
// shard's current 16th-best dist (float bits, dist>=0 so uint order == float
// order). Rejecting dist > tau is exact: tau >= final global 16th-best.
__global__ __launch_bounds__(256, 4) void knn_kernel(const float4* __restrict__ pc,
                                                     int* __restrict__ idx) {
    __shared__ u64 smem[256 * 17]; // lane buffers (cap 16, stride 17) then merge tree
    __shared__ unsigned tauS[QPB];

    const int tid = threadIdx.x;
    const int q = tid & (QPB - 1);
    const int s = tid >> 4;
    const int n = blockIdx.x * QPB + q;
    const int base = (n >= HALF_N) ? HALF_N : 0;
    const float4 p = pc[n];

    if (tid < QPB) tauS[tid] = 0x7f800000u; // +inf
    u64 L[16];
#pragma unroll
    for (int j = 0; j < 16; ++j) L[j] = ~0ULL;

    u64* buf = &smem[tid * 17];
    int cnt = 0;
    __syncthreads();

    const int c0 = base + s * MCAND;
#pragma unroll 1
    for (int t0 = 0; t0 < MCAND; t0 += CHUNK) {
        const float tauf = __uint_as_float(tauS[q]); // stale-read OK (conservative)
#pragma unroll
        for (int dt = 0; dt < CHUNK; ++dt) {
            const int ci = c0 + t0 + dt;
            const float4 cp = pc[ci];
            float dot = __fadd_rn(__fadd_rn(__fmul_rn(p.x, cp.x), __fmul_rn(p.y, cp.y)),
                                  __fmul_rn(p.z, cp.z));
            float dist = __fsub_rn(__fadd_rn(p.w, cp.w), __fmul_rn(2.0f, dot));
            if (!(dist > tauf)) { // ties admitted; exact select at flush
                buf[cnt] = ((u64)__float_as_uint(dist) << 32) | (unsigned)ci;
                ++cnt;
            }
        }
        if (__any(cnt >= FTHRESH)) {
            unsigned tb = flush16(L, buf, cnt);
            atomicMin(&tauS[q], tb);
        }
        // invariant: cnt <= 11 after check, +4 per chunk -> <= 15 <= 16 cap
    }
    flush16(L, buf, cnt);

    // cross-shard bitonic merge tree in LDS
    __syncthreads();
#pragma unroll
    for (int j = 0; j < 16; ++j) smem[tid * 17 + j] = L[j];
    __syncthreads();
    for (int step = SHARDS / 2; step >= 1; step >>= 1) {
        if (s < step) {
            u64 B[16];
#pragma unroll
            for (int j = 0; j < 16; ++j) B[j] = smem[((s + step) * QPB + q) * 17 + j];
            merge16(L, B);
#pragma unroll
            for (int j = 0; j < 16; ++j) smem[(s * QPB + q) * 17 + j] = L[j];
        }
        __syncthreads();
    }

    if (s == 0) {
#pragma unroll
        for (int j = 0; j < 16; ++j) idx[n * KK + j] = (int)(L[j] & 0xffffffffULL);
    }
}

// ============ per-layer conv: h once -> {part sums, raw per-point max} ============
// MODE 0: xin = pts (stride 5, offset 1, raw). MODE 1: xin = m_prev, apply
// relu(fma(., A, B2)) of the PREVIOUS layer on the fly (A>0, so
// max-then-affine == affine-then-max; relu monotone).
template <int IN_C, int OUT_C, int MODE>
__global__ __launch_bounds__(256) void convS_kernel(const float* __restrict__ xin,
                                                    const float* __restrict__ statsPrev,
                                                    const int* __restrict__ idxg,
                                                    const float* __restrict__ W,
                                                    const float* __restrict__ bb,
                                                    float* __restrict__ part,
                                                    float* __restrict__ mout) {
    constexpr int RED = 256 / OUT_C;
    __shared__ float hbuf[OUT_C][257];
    __shared__ float pr1[OUT_C][RED + 1];
    __shared__ float pr2[OUT_C][RED + 1];
    __shared__ float2 sAB[IN_C];

    const int tid = threadIdx.x;
    const int gt = blockIdx.x * 256 + tid;
    const int n = gt >> 4;

    if (MODE == 1) {
        if (tid < IN_C) sAB[tid] = make_float2(statsPrev[tid], statsPrev[32 + tid]);
        __syncthreads();
    }

    float xn[IN_C], dx[IN_C];
    const int j = idxg[gt];
    if (MODE == 0) {
        const float* rn = xin + n * 5 + 1;
        const float* rj = xin + j * 5 + 1;
#pragma unroll
        for (int e = 0; e < IN_C; ++e) xn[e] = rn[e];
#pragma unroll
        for (int e = 0; e < IN_C; ++e) dx[e] = rj[e] - xn[e];
    } else {
        const float4* rn = (const float4*)(xin + n * IN_C);
        const float4* rj = (const float4*)(xin + j * IN_C);
#pragma unroll
        for (int e4 = 0; e4 < IN_C / 4; ++e4) {
            float4 a = rn[e4];
            float4 bq = rj[e4];
            float av[4] = {a.x, a.y, a.z, a.w};
            float bv[4] = {bq.x, bq.y, bq.z, bq.w};
#pragma unroll
            for (int u = 0; u < 4; ++u) {
                float2 ab = sAB[4 * e4 + u];
                float xv = fmaxf(fmaf(av[u], ab.x, ab.y), 0.f);
                float jv = fmaxf(fmaf(bv[u], ab.x, ab.y), 0.f);
                xn[4 * e4 + u] = xv;
                dx[4 * e4 + u] = jv - xv;
            }
        }
    }

    float h[OUT_C];
#pragma unroll
    for (int c = 0; c < OUT_C; ++c) {
        float acc = bb[c];
#pragma unroll
        for (int e = 0; e < IN_C; ++e) acc = fmaf(W[c * 2 * IN_C + e], xn[e], acc);
#pragma unroll
        for (int e = 0; e < IN_C; ++e) acc = fmaf(W[c * 2 * IN_C + IN_C + e], dx[e], acc);
        h[c] = acc;
    }

    // ---- raw max over K=16 via shfl (16 consecutive lanes share n) ----
    {
        const int kq = tid & 15;
        if (OUT_C == 32) {
            float w0 = 0.f, w1 = 0.f;
#pragma unroll
            for (int c = 0; c < OUT_C; ++c) {
                float v = h[c];
                v = fmaxf(v, __shfl_xor(v, 1));
                v = fmaxf(v, __shfl_xor(v, 2));
                v = fmaxf(v, __shfl_xor(v, 4));
                v = fmaxf(v, __shfl_xor(v, 8));
                if (c == 2 * kq)     w0 = v;
                if (c == 2 * kq + 1) w1 = v;
            }
            *reinterpret_cast<float2*>(mout + n * 32 + 2 * kq) = make_float2(w0, w1);
        } else {
            float w0 = 0.f;
#pragma unroll
            for (int c = 0; c < OUT_C; ++c) {
                float v = h[c];
                v = fmaxf(v, __shfl_xor(v, 1));
                v = fmaxf(v, __shfl_xor(v, 2));
                v = fmaxf(v, __shfl_xor(v, 4));
                v = fmaxf(v, __shfl_xor(v, 8));
                if (c == kq) w0 = v;
            }
            mout[n * 16 + kq] = w0;
        }
    }

    // ---- block reduce sum/sumsq (deterministic) ----
#pragma unroll
    for (int c = 0; c < OUT_C; ++c) hbuf[c][tid] = h[c];
    __syncthreads();
    {
        const int c2 = tid & (OUT_C - 1);
        const int ch = tid / OUT_C;
        float s1 = 0.f, s2 = 0.f;
#pragma unroll
        for (int i = 0; i < OUT_C; ++i) {
            float hh = hbuf[c2][ch * OUT_C + i];
            s1 += hh; s2 += hh * hh;
        }
        pr1[c2][ch] = s1;
        pr2[c2][ch] = s2;
    }
    __syncthreads();
    if (tid < OUT_C) {
        float t1 = 0.f, t2 = 0.f;
#pragma unroll
        for (int k = 0; k < RED; ++k) { t1 += pr1[tid][k]; t2 += pr2[tid][k]; }
        part[blockIdx.x * 64 + tid]      = t1;
        part[blockIdx.x * 64 + 32 + tid] = t2;
    }
}

// ---------------- finalize: part -> A[c]=rs*g, B2[c]=t-mu*A ----------------
template <int OUT_C>
__global__ __launch_bounds__(256) void finalize_kernel(const float* __restrict__ part,
                                                       const float* __restrict__ g,
                                                       const float* __restrict__ t,
                                                       float* __restrict__ statsL) {
    __shared__ float red[4][64];
    __shared__ float tot[64];
    const int tid = threadIdx.x;
    const int c2 = tid & 63, ch = tid >> 6;
    float s = 0.f;
    for (int bk = ch * 256; bk < ch * 256 + 256; ++bk) s += part[bk * 64 + c2];
    red[ch][c2] = s;
    __syncthreads();
    if (tid < 64) tot[tid] = red[0][tid] + red[1][tid] + red[2][tid] + red[3][tid];
    __syncthreads();
    if (tid < OUT_C) {
        const float inv = 1.0f / (float)NK;
        float mu  = tot[tid] * inv;
        float var = tot[32 + tid] * inv - mu * mu;
        float rs  = 1.0f / sqrtf(var + EPSV);
        float A   = rs * g[tid];
        statsL[tid]      = A;
        statsL[32 + tid] = t[tid] - mu * A;
    }
}

// ---- fused finalize(layer3) + apply: every block redundantly reduces part
// (deterministic fixed order), then applies relu(affine(m3)) to its slice ----
__global__ __launch_bounds__(256) void finapply_kernel(const float* __restrict__ part,
                                                       const float* __restrict__ g,
                                                       const float* __restrict__ t,
                                                       const float* __restrict__ m,
                                                       float* __restrict__ out) {
    __shared__ float red[4][64];
    __shared__ float tot[64];
    __shared__ float sA[32], sB[32];
    const int tid = threadIdx.x;
    const int c2 = tid & 63, ch = tid >> 6;
    float s = 0.f;
    for (int bk = ch * 256; bk < ch * 256 + 256; ++bk) s += part[bk * 64 + c2];
    red[ch][c2] = s;
    __syncthreads();
    if (tid < 64) tot[tid] = red[0][tid] + red[1][tid] + red[2][tid] + red[3][tid];
    __syncthreads();
    if (tid < 32) {
        const float inv = 1.0f / (float)NK;
        float mu  = tot[tid] * inv;
        float var = tot[32 + tid] * inv - mu * mu;
        float rs  = 1.0f / sqrtf(var + EPSV);
        float A   = rs * g[tid];
        sA[tid] = A;
        sB[tid] = t[tid] - mu * A;
    }
    __syncthreads();
    // apply: grid 64 blocks x 2048 float4 each
    const int base = blockIdx.x * 2048 + tid;
#pragma unroll
    for (int r = 0; r < 8; ++r) {
        const int i = base + r * 256;
        float4 mv = ((const float4*)m)[i];
        const int c0 = (i * 4) & 31;
        float4 o;
        o.x = fmaxf(fmaf(mv.x, sA[c0 + 0], sB[c0 + 0]), 0.f);
        o.y = fmaxf(fmaf(mv.y, sA[c0 + 1], sB[c0 + 1]), 0.f);
        o.z = fmaxf(fmaf(mv.z, sA[c0 + 2], sB[c0 + 2]), 0.f);
        o.w = fmaxf(fmaf(mv.w, sA[c0 + 3], sB[c0 + 3]), 0.f);
        ((float4*)out)[i] = o;
    }
}

extern "C" void kernel_launch(void* const* d_in, const int* in_sizes, int n_in,
                              void* d_out, int out_size, void* d_ws, size_t ws_size,
                              hipStream_t stream) {
    const float* pts = (const float*)d_in[0];
    const float* Wl[4], *bl[4], *gl[4], *tl[4];
    for (int l = 0; l < 4; ++l) {
        Wl[l] = (const float*)d_in[1 + 4 * l + 0];
        bl[l] = (const float*)d_in[1 + 4 * l + 1];
        gl[l] = (const float*)d_in[1 + 4 * l + 2];
        tl[l] = (const float*)d_in[1 + 4 * l + 3];
    }
    char* ws = (char*)d_ws;
    int*    idx   = (int*)(ws + OFF_IDX);
    float4* pc    = (float4*)(ws + OFF_PC);
    float*  m0    = (float*)(ws + OFF_MA); // [N][16]
    float*  m1    = (float*)(ws + OFF_MB); // [N][16]
    float*  m2    = (float*)(ws + OFF_MC); // [N][32]
    float*  m3    = (float*)(ws + OFF_MA); // [N][32] reuses MA|MB (m0,m1 dead)
    float*  part  = (float*)(ws + OFF_PART);
    float*  stats = (float*)(ws + OFF_STATS); // [4][64]
    float*  out   = (float*)d_out;

    prep_kernel<<<N_PTS / 256, 256, 0, stream>>>(pts, pc);
    knn_kernel<<<N_PTS / QPB, 256, 0, stream>>>(pc, idx);

    const int GA = NK / 256; // 1024 blocks

    // layer 0: 4 -> 16 (raw pts input)
    convS_kernel<4, 16, 0><<<GA, 256, 0, stream>>>(pts, nullptr, idx, Wl[0], bl[0], part, m0);
    finalize_kernel<16><<<1, 256, 0, stream>>>(part, gl[0], tl[0], stats + 0);

    // layer 1: 16 -> 16 (m0 + layer-0 affine on the fly)
    convS_kernel<16, 16, 1><<<GA, 256, 0, stream>>>(m0, stats + 0, idx, Wl[1], bl[1], part, m1);
    finalize_kernel<16><<<1, 256, 0, stream>>>(part, gl[1], tl[1], stats + 64);

    // layer 2: 16 -> 32
    convS_kernel<16, 32, 1><<<GA, 256, 0, stream>>>(m1, stats + 64, idx, Wl[2], bl[2], part, m2);
    finalize_kernel<32><<<1, 256, 0, stream>>>(part, gl[2], tl[2], stats + 128);

    // layer 3: 32 -> 32 (writes m3 over MA|MB; m0/m1 dead)
    convS_kernel<32, 32, 1><<<GA, 256, 0, stream>>>(m2, stats + 128, idx, Wl[3], bl[3], part, m3);

    // fused finalize(layer3) + out = relu(affine(m3))
    finapply_kernel<<<64, 256, 0, stream>>>(part, gl[3], tl[3], m3, out);
}